// Round 1
// baseline (419.173 us; speedup 1.0000x reference)
//
#include <hip/hip_runtime.h>
#include <math.h>

#define B_    1024
#define LK_   1024
#define LQD_  256
#define SQD_  128
#define EPSLN 1e-6f
#define LOG2E 1.4426950408889634f

__device__ __forceinline__ float gelu_exact(float x) {
    return 0.5f * x * (1.0f + erff(x * 0.70710678118654752f));
}

// One block per batch element b. 256 threads = 4 waves.
// Computes the entire q-path: LN1 -> W1 -> GELU -> LNq -> Wq -> (u-vector trick)
// -> streaming masked online-softmax attention over 1024 keys
// -> Wv/Wo epilogue -> residual -> q_out and sc_ws = q_atten_final * scale_w.
__global__ __launch_bounds__(256, 4)
void fused_q_attn_kernel(
    const float* __restrict__ q_feats, const float* __restrict__ k_feats,
    const int*   __restrict__ msk,
    const float* __restrict__ ln1_g, const float* __restrict__ ln1_b,
    const float* __restrict__ W1,    const float* __restrict__ b1,
    const float* __restrict__ lnq_g, const float* __restrict__ lnq_b,
    const float* __restrict__ lnk_g, const float* __restrict__ lnk_b,
    const float* __restrict__ Wq,    const float* __restrict__ bq,
    const float* __restrict__ Wk,    const float* __restrict__ bk,
    const float* __restrict__ Wv,    const float* __restrict__ bv,
    const float* __restrict__ Wo,    const float* __restrict__ bo,
    const float* __restrict__ scale_w,
    const float* __restrict__ ln2_g, const float* __restrict__ ln2_b,
    const float* __restrict__ W2,    const float* __restrict__ b2,
    float* __restrict__ q_out, float* __restrict__ sc_ws)
{
    const int b    = blockIdx.x;
    const int tid  = threadIdx.x;
    const int wave = tid >> 6;
    const int lane = tid & 63;

    __shared__ float s_qn[256];
    __shared__ float s_q1[128];
    __shared__ float s_qi[128];
    __shared__ float s_qh[128];
    __shared__ float s_u[2][128];
    __shared__ float s_c[2];
    __shared__ float s_red[8];
    __shared__ int   s_idx[4][256];
    __shared__ float s_w[4][2][128];
    __shared__ float s_ml[4][2][2];
    __shared__ float s_wn[2][128];
    __shared__ float s_ctx[128];
    __shared__ float s_qa[128];
    __shared__ float s_qn2[128];

    // ---------- prologue: LN1(q_feats[b], 256) ----------
    float x = q_feats[b * LQD_ + tid];
    float rs = x, rss = x * x;
    #pragma unroll
    for (int o = 32; o >= 1; o >>= 1) { rs += __shfl_xor(rs, o); rss += __shfl_xor(rss, o); }
    if (lane == 0) { s_red[wave * 2] = rs; s_red[wave * 2 + 1] = rss; }
    __syncthreads();
    {
        float sum  = s_red[0] + s_red[2] + s_red[4] + s_red[6];
        float ssum = s_red[1] + s_red[3] + s_red[5] + s_red[7];
        float mu   = sum * (1.0f / 256.0f);
        float var  = ssum * (1.0f / 256.0f) - mu * mu;
        float rstd = rsqrtf(var + EPSLN);
        s_qn[tid] = (x - mu) * rstd * ln1_g[tid] + ln1_b[tid];
    }
    __syncthreads();

    // h1 = s_qn @ W1 + b1 ; q1 = gelu(h1)
    if (tid < 128) {
        float acc = b1[tid];
        for (int c = 0; c < 256; ++c) acc = fmaf(s_qn[c], W1[c * 128 + tid], acc);
        s_q1[tid] = gelu_exact(acc);
    }
    __syncthreads();

    // LNq(q1) over 128
    float v1 = (tid < 128) ? s_q1[tid] : 0.0f;
    rs = v1; rss = v1 * v1;
    #pragma unroll
    for (int o = 32; o >= 1; o >>= 1) { rs += __shfl_xor(rs, o); rss += __shfl_xor(rss, o); }
    __syncthreads();                      // protect s_red reuse
    if (lane == 0) { s_red[wave * 2] = rs; s_red[wave * 2 + 1] = rss; }
    __syncthreads();
    {
        float sum  = s_red[0] + s_red[2] + s_red[4] + s_red[6];
        float ssum = s_red[1] + s_red[3] + s_red[5] + s_red[7];
        float mu   = sum * (1.0f / 128.0f);
        float var  = ssum * (1.0f / 128.0f) - mu * mu;
        float rstd = rsqrtf(var + EPSLN);
        if (tid < 128) s_qi[tid] = (v1 - mu) * rstd * lnq_g[tid] + lnq_b[tid];
    }
    __syncthreads();

    // qh = s_qi @ Wq + bq
    if (tid < 128) {
        float acc = bq[tid];
        for (int c = 0; c < 128; ++c) acc = fmaf(s_qi[c], Wq[c * 128 + tid], acc);
        s_qh[tid] = acc;
    }
    __syncthreads();

    // u_h[c] = sum_e Wk[c, h*64+e] * qh[h*64+e]   (score vectors), fold 1/8 and log2e
    const float SCL = 0.125f * LOG2E;
    if (tid < 128) {
        float a0 = 0.f, a1 = 0.f;
        for (int e = 0; e < 64; ++e) {
            a0 = fmaf(Wk[tid * 128 + e],      s_qh[e],      a0);
            a1 = fmaf(Wk[tid * 128 + 64 + e], s_qh[64 + e], a1);
        }
        s_u[0][tid] = a0 * SCL;
        s_u[1][tid] = a1 * SCL;
    }
    if (tid == 0) { float a = 0.f; for (int e = 0; e < 64; ++e) a = fmaf(bk[e],      s_qh[e],      a); s_c[0] = a * SCL; }
    if (tid == 1) { float a = 0.f; for (int e = 0; e < 64; ++e) a = fmaf(bk[64 + e], s_qh[64 + e], a); s_c[1] = a * SCL; }

    // ---------- mask compaction: wave w owns rows [w*256, w*256+256) ----------
    const int* mrow = msk + b * LK_;
    int cnt = 0;
    #pragma unroll
    for (int i = 0; i < 4; ++i) {
        int r = (wave << 8) + (i << 6) + lane;
        int mk = mrow[r];
        unsigned long long bal = __ballot(mk != 0);
        int pre = __popcll(bal & ((1ull << lane) - 1ull));
        if (mk) s_idx[wave][cnt + pre] = r;
        cnt += __popcll(bal);
    }
    __syncthreads();   // also makes s_u/s_c visible to all waves

    // per-lane constants: lane owns columns 2*lane, 2*lane+1
    const int  c0i = lane * 2, c1i = lane * 2 + 1;
    const float g0  = lnk_g[c0i], g1  = lnk_g[c1i];
    const float hb0 = lnk_b[c0i], hb1 = lnk_b[c1i];
    const float u00 = s_u[0][c0i], u01 = s_u[0][c1i];
    const float u10 = s_u[1][c0i], u11 = s_u[1][c1i];
    const float cc0 = s_c[0],      cc1 = s_c[1];

    const float2* kf2 = (const float2*)(k_feats) + (size_t)b * (LK_ * (SQD_ / 2));

    // ---------- streaming online-softmax attention ----------
    float m0 = -1e30f, l0 = 0.f, w00 = 0.f, w01 = 0.f;
    float m1 = -1e30f, l1 = 0.f, w10 = 0.f, w11 = 0.f;

    float2 xv = make_float2(0.f, 0.f);
    if (cnt > 0) xv = kf2[s_idx[wave][0] * 64 + lane];
    for (int t = 0; t < cnt; ++t) {
        float2 xn = make_float2(0.f, 0.f);
        if (t + 1 < cnt) xn = kf2[s_idx[wave][t + 1] * 64 + lane];

        // LN stats over the 128-dim row
        float a = xv.x + xv.y;
        float q = xv.x * xv.x + xv.y * xv.y;
        #pragma unroll
        for (int o = 32; o >= 1; o >>= 1) { a += __shfl_xor(a, o); q += __shfl_xor(q, o); }
        float mu2 = a * (1.f / 128.f);
        float vr  = q * (1.f / 128.f) - mu2 * mu2;
        float rs2 = rsqrtf(vr + EPSLN);
        float kv0 = (xv.x - mu2) * rs2 * g0 + hb0;
        float kv1 = (xv.y - mu2) * rs2 * g1 + hb1;

        // scores (log2 domain)
        float p0 = kv0 * u00 + kv1 * u01;
        float p1 = kv0 * u10 + kv1 * u11;
        #pragma unroll
        for (int o = 32; o >= 1; o >>= 1) { p0 += __shfl_xor(p0, o); p1 += __shfl_xor(p1, o); }
        float sc0 = p0 + cc0, sc1 = p1 + cc1;

        // online softmax update, head 0
        float mn0 = fmaxf(m0, sc0);
        float cr0 = exp2f(m0 - mn0);
        float pp0 = exp2f(sc0 - mn0);
        m0 = mn0; l0 = l0 * cr0 + pp0;
        w00 = w00 * cr0 + pp0 * kv0;
        w01 = w01 * cr0 + pp0 * kv1;
        // head 1
        float mn1 = fmaxf(m1, sc1);
        float cr1 = exp2f(m1 - mn1);
        float pp1 = exp2f(sc1 - mn1);
        m1 = mn1; l1 = l1 * cr1 + pp1;
        w10 = w10 * cr1 + pp1 * kv0;
        w11 = w11 * cr1 + pp1 * kv1;

        xv = xn;
    }

    // ---------- merge 4 waves' online-softmax partials ----------
    s_w[wave][0][c0i] = w00; s_w[wave][0][c1i] = w01;
    s_w[wave][1][c0i] = w10; s_w[wave][1][c1i] = w11;
    if (lane == 0) {
        s_ml[wave][0][0] = m0; s_ml[wave][0][1] = l0;
        s_ml[wave][1][0] = m1; s_ml[wave][1][1] = l1;
    }
    __syncthreads();

    if (tid < 128) {
        #pragma unroll
        for (int h = 0; h < 2; ++h) {
            float mg = fmaxf(fmaxf(s_ml[0][h][0], s_ml[1][h][0]),
                             fmaxf(s_ml[2][h][0], s_ml[3][h][0]));
            float lt = 0.f, wt = 0.f;
            #pragma unroll
            for (int wv = 0; wv < 4; ++wv) {
                float e = exp2f(s_ml[wv][h][0] - mg);
                lt += s_ml[wv][h][1] * e;
                wt += s_w[wv][h][tid] * e;
            }
            s_wn[h][tid] = wt / lt;
        }
    }
    __syncthreads();

    // ctx = (w/l) @ Wv + bv
    if (tid < 128) {
        int h = tid >> 6;
        float acc = bv[tid];
        for (int c = 0; c < 128; ++c) acc = fmaf(s_wn[h][c], Wv[c * 128 + tid], acc);
        s_ctx[tid] = acc;
    }
    __syncthreads();

    // attn_out = gelu(ctx @ Wo + bo); q_atten_final = q1 + attn_out
    if (tid < 128) {
        float acc = bo[tid];
        for (int c = 0; c < 128; ++c) acc = fmaf(s_ctx[c], Wo[c * 128 + tid], acc);
        float qa = s_q1[tid] + gelu_exact(acc);
        s_qa[tid] = qa;
        sc_ws[b * 128 + tid] = qa * scale_w[tid];
    }
    __syncthreads();

    // LN2(q_atten_final) over 128
    float v2 = (tid < 128) ? s_qa[tid] : 0.0f;
    rs = v2; rss = v2 * v2;
    #pragma unroll
    for (int o = 32; o >= 1; o >>= 1) { rs += __shfl_xor(rs, o); rss += __shfl_xor(rss, o); }
    __syncthreads();                      // protect s_red reuse
    if (lane == 0) { s_red[wave * 2] = rs; s_red[wave * 2 + 1] = rss; }
    __syncthreads();
    {
        float sum  = s_red[0] + s_red[2] + s_red[4] + s_red[6];
        float ssum = s_red[1] + s_red[3] + s_red[5] + s_red[7];
        float mu   = sum * (1.0f / 128.0f);
        float var  = ssum * (1.0f / 128.0f) - mu * mu;
        float rstd = rsqrtf(var + EPSLN);
        if (tid < 128) s_qn2[tid] = (v2 - mu) * rstd * ln2_g[tid] + ln2_b[tid];
    }
    __syncthreads();

    // q_out = q_feats + gelu(qn2 @ W2 + b2)   (256 outputs, one per thread)
    {
        float acc = b2[tid];
        for (int c = 0; c < 128; ++c) acc = fmaf(s_qn2[c], W2[c * 256 + tid], acc);
        q_out[b * LQD_ + tid] = q_feats[b * LQD_ + tid] + gelu_exact(acc);
    }
}

// k_out[b, j, :] = k_feats[b, j, :] + sc[j, :]
__global__ __launch_bounds__(256)
void kout_kernel(const float4* __restrict__ kf,
                 const float4* __restrict__ sc,
                 float4* __restrict__ out)
{
    const int total4 = B_ * LK_ * (SQD_ / 4);  // 33,554,432
    const int stride = gridDim.x * blockDim.x;
    for (int idx = blockIdx.x * blockDim.x + threadIdx.x; idx < total4; idx += stride) {
        float4 k = kf[idx];
        int j = (idx >> 5) & (LK_ - 1);
        float4 s = sc[(j << 5) + (idx & 31)];
        float4 o;
        o.x = k.x + s.x; o.y = k.y + s.y; o.z = k.z + s.z; o.w = k.w + s.w;
        out[idx] = o;
    }
}

extern "C" void kernel_launch(void* const* d_in, const int* in_sizes, int n_in,
                              void* d_out, int out_size, void* d_ws, size_t ws_size,
                              hipStream_t stream)
{
    (void)in_sizes; (void)n_in; (void)out_size; (void)ws_size;
    const float* q_feats = (const float*)d_in[0];
    const float* k_feats = (const float*)d_in[1];
    const int*   msk     = (const int*)d_in[2];
    const float* ln1_g   = (const float*)d_in[3];
    const float* ln1_b   = (const float*)d_in[4];
    const float* W1      = (const float*)d_in[5];
    const float* b1      = (const float*)d_in[6];
    const float* lnq_g   = (const float*)d_in[7];
    const float* lnq_b   = (const float*)d_in[8];
    const float* lnk_g   = (const float*)d_in[9];
    const float* lnk_b   = (const float*)d_in[10];
    const float* Wq      = (const float*)d_in[11];
    const float* bq      = (const float*)d_in[12];
    const float* Wk      = (const float*)d_in[13];
    const float* bk      = (const float*)d_in[14];
    const float* Wv      = (const float*)d_in[15];
    const float* bv      = (const float*)d_in[16];
    const float* Wo      = (const float*)d_in[17];
    const float* bo      = (const float*)d_in[18];
    const float* scale_w = (const float*)d_in[19];
    const float* ln2_g   = (const float*)d_in[20];
    const float* ln2_b   = (const float*)d_in[21];
    const float* W2      = (const float*)d_in[22];
    const float* b2      = (const float*)d_in[23];

    float* q_out = (float*)d_out;                           // 1024*256
    float* k_out = (float*)d_out + (size_t)B_ * LQD_;       // 1024*1024*128
    float* sc_ws = (float*)d_ws;                            // 1024*128 f32 = 512 KB

    fused_q_attn_kernel<<<B_, 256, 0, stream>>>(
        q_feats, k_feats, msk, ln1_g, ln1_b, W1, b1, lnq_g, lnq_b,
        lnk_g, lnk_b, Wq, bq, Wk, bk, Wv, bv, Wo, bo, scale_w,
        ln2_g, ln2_b, W2, b2, q_out, sc_ws);

    kout_kernel<<<2048, 256, 0, stream>>>(
        (const float4*)k_feats, (const float4*)sc_ws, (float4*)k_out);
}

// Round 2
// 386.986 us; speedup vs baseline: 1.0832x; 1.0832x over previous
//
#include <hip/hip_runtime.h>
#include <math.h>

#define B_    1024
#define LK_   1024
#define LQD_  256
#define SQD_  128
#define EPSLN 1e-6f
#define LOG2E 1.4426950408889634f

__device__ __forceinline__ float gelu_exact(float x) {
    return 0.5f * x * (1.0f + erff(x * 0.70710678118654752f));
}

// One block per batch element b (grid = 1024). 256 threads = 4 waves.
// Phase 1: entire q-path (LN1 -> W1 -> GELU -> LNq -> Wq -> u-vector trick ->
//          streaming masked online-softmax attention -> Wv/Wo epilogue ->
//          residual -> q_out, and sc[b] = q_atten_final * scale_w in LDS).
// Phase 2: stream column b of k_out: k_out[b2, b, :] = k_feats[b2, b, :] + sc[b].
// No cross-block dependency: column j of k_out only needs sc[j].
__global__ __launch_bounds__(256, 4)
void fused_joint_kernel(
    const float* __restrict__ q_feats, const float* __restrict__ k_feats,
    const int*   __restrict__ msk,
    const float* __restrict__ ln1_g, const float* __restrict__ ln1_b,
    const float* __restrict__ W1,    const float* __restrict__ b1,
    const float* __restrict__ lnq_g, const float* __restrict__ lnq_b,
    const float* __restrict__ lnk_g, const float* __restrict__ lnk_b,
    const float* __restrict__ Wq,    const float* __restrict__ bq,
    const float* __restrict__ Wk,    const float* __restrict__ bk,
    const float* __restrict__ Wv,    const float* __restrict__ bv,
    const float* __restrict__ Wo,    const float* __restrict__ bo,
    const float* __restrict__ scale_w,
    const float* __restrict__ ln2_g, const float* __restrict__ ln2_b,
    const float* __restrict__ W2,    const float* __restrict__ b2,
    float* __restrict__ q_out, float* __restrict__ k_out)
{
    const int b    = blockIdx.x;
    const int tid  = threadIdx.x;
    const int wave = tid >> 6;
    const int lane = tid & 63;

    __shared__ float s_qn[256];
    __shared__ float s_q1[128];
    __shared__ float s_qi[128];
    __shared__ float s_qh[128];
    __shared__ float s_u[2][128];
    __shared__ float s_c[2];
    __shared__ float s_red[8];
    __shared__ int   s_idx[4][256];
    __shared__ float s_w[4][2][128];
    __shared__ float s_ml[4][2][2];
    __shared__ float s_wn[2][128];
    __shared__ float s_ctx[128];
    __shared__ float s_qa[128];
    __shared__ float s_qn2[128];
    __shared__ float s_sc[128];

    // ---------- prologue: LN1(q_feats[b], 256) ----------
    float x = q_feats[b * LQD_ + tid];
    float rs = x, rss = x * x;
    #pragma unroll
    for (int o = 32; o >= 1; o >>= 1) { rs += __shfl_xor(rs, o); rss += __shfl_xor(rss, o); }
    if (lane == 0) { s_red[wave * 2] = rs; s_red[wave * 2 + 1] = rss; }
    __syncthreads();
    {
        float sum  = s_red[0] + s_red[2] + s_red[4] + s_red[6];
        float ssum = s_red[1] + s_red[3] + s_red[5] + s_red[7];
        float mu   = sum * (1.0f / 256.0f);
        float var  = ssum * (1.0f / 256.0f) - mu * mu;
        float rstd = rsqrtf(var + EPSLN);
        s_qn[tid] = (x - mu) * rstd * ln1_g[tid] + ln1_b[tid];
    }
    __syncthreads();

    // h1 = s_qn @ W1 + b1 ; q1 = gelu(h1)
    if (tid < 128) {
        float acc = b1[tid];
        #pragma unroll 4
        for (int c = 0; c < 256; ++c) acc = fmaf(s_qn[c], W1[c * 128 + tid], acc);
        s_q1[tid] = gelu_exact(acc);
    }
    __syncthreads();

    // LNq(q1) over 128
    float v1 = (tid < 128) ? s_q1[tid] : 0.0f;
    rs = v1; rss = v1 * v1;
    #pragma unroll
    for (int o = 32; o >= 1; o >>= 1) { rs += __shfl_xor(rs, o); rss += __shfl_xor(rss, o); }
    __syncthreads();                      // protect s_red reuse
    if (lane == 0) { s_red[wave * 2] = rs; s_red[wave * 2 + 1] = rss; }
    __syncthreads();
    {
        float sum  = s_red[0] + s_red[2] + s_red[4] + s_red[6];
        float ssum = s_red[1] + s_red[3] + s_red[5] + s_red[7];
        float mu   = sum * (1.0f / 128.0f);
        float var  = ssum * (1.0f / 128.0f) - mu * mu;
        float rstd = rsqrtf(var + EPSLN);
        if (tid < 128) s_qi[tid] = (v1 - mu) * rstd * lnq_g[tid] + lnq_b[tid];
    }
    __syncthreads();

    // qh = s_qi @ Wq + bq
    if (tid < 128) {
        float acc = bq[tid];
        #pragma unroll 4
        for (int c = 0; c < 128; ++c) acc = fmaf(s_qi[c], Wq[c * 128 + tid], acc);
        s_qh[tid] = acc;
    }
    __syncthreads();

    // u_h[c] = sum_e Wk[c, h*64+e] * qh[h*64+e]   (score vectors), fold 1/8 and log2e
    const float SCL = 0.125f * LOG2E;
    if (tid < 128) {
        float a0 = 0.f, a1 = 0.f;
        #pragma unroll 4
        for (int e = 0; e < 64; ++e) {
            a0 = fmaf(Wk[tid * 128 + e],      s_qh[e],      a0);
            a1 = fmaf(Wk[tid * 128 + 64 + e], s_qh[64 + e], a1);
        }
        s_u[0][tid] = a0 * SCL;
        s_u[1][tid] = a1 * SCL;
    }
    if (tid == 0) { float a = 0.f; for (int e = 0; e < 64; ++e) a = fmaf(bk[e],      s_qh[e],      a); s_c[0] = a * SCL; }
    if (tid == 1) { float a = 0.f; for (int e = 0; e < 64; ++e) a = fmaf(bk[64 + e], s_qh[64 + e], a); s_c[1] = a * SCL; }

    // ---------- mask compaction: wave w owns rows [w*256, w*256+256) ----------
    const int* mrow = msk + b * LK_;
    int cnt = 0;
    #pragma unroll
    for (int i = 0; i < 4; ++i) {
        int r = (wave << 8) + (i << 6) + lane;
        int mk = mrow[r];
        unsigned long long bal = __ballot(mk != 0);
        int pre = __popcll(bal & ((1ull << lane) - 1ull));
        if (mk) s_idx[wave][cnt + pre] = r;
        cnt += __popcll(bal);
    }
    __syncthreads();   // also makes s_u/s_c visible to all waves

    // per-lane constants: lane owns columns 2*lane, 2*lane+1
    const int  c0i = lane * 2, c1i = lane * 2 + 1;
    const float g0  = lnk_g[c0i], g1  = lnk_g[c1i];
    const float hb0 = lnk_b[c0i], hb1 = lnk_b[c1i];
    const float u00 = s_u[0][c0i], u01 = s_u[0][c1i];
    const float u10 = s_u[1][c0i], u11 = s_u[1][c1i];
    const float cc0 = s_c[0],      cc1 = s_c[1];

    // fused-score constants: score_h = rstd*(P_h - mu*sgu_h) + d_h
    //   P_h = sum_c x[c]*g[c]*u_h[c];  sgu_h = sum_c g[c]*u_h[c];
    //   d_h = sum_c lnk_b[c]*u_h[c] + cc_h
    const float gu00 = g0 * u00, gu01 = g1 * u01;
    const float gu10 = g0 * u10, gu11 = g1 * u11;
    float sgu0 = gu00 + gu01;
    float sgu1 = gu10 + gu11;
    float dd0  = fmaf(hb0, u00, hb1 * u01);
    float dd1  = fmaf(hb0, u10, hb1 * u11);
    #pragma unroll
    for (int o = 32; o >= 1; o >>= 1) {
        sgu0 += __shfl_xor(sgu0, o); sgu1 += __shfl_xor(sgu1, o);
        dd0  += __shfl_xor(dd0,  o); dd1  += __shfl_xor(dd1,  o);
    }
    const float d0 = dd0 + cc0, d1 = dd1 + cc1;

    const float2* kf2 = (const float2*)(k_feats) + (size_t)b * (LK_ * (SQD_ / 2));

    // ---------- streaming online-softmax attention ----------
    float m0 = -1e30f, l0 = 0.f, w00 = 0.f, w01 = 0.f;
    float m1 = -1e30f, l1 = 0.f, w10 = 0.f, w11 = 0.f;

    #define ROW_STEP(xx, valid)                                               \
    {                                                                         \
        float a_  = xx.x + xx.y;                                              \
        float q_  = fmaf(xx.x, xx.x, xx.y * xx.y);                            \
        float p0_ = fmaf(xx.x, gu00, xx.y * gu01);                            \
        float p1_ = fmaf(xx.x, gu10, xx.y * gu11);                            \
        _Pragma("unroll")                                                     \
        for (int o_ = 32; o_ >= 1; o_ >>= 1) {                                \
            a_  += __shfl_xor(a_,  o_); q_  += __shfl_xor(q_,  o_);           \
            p0_ += __shfl_xor(p0_, o_); p1_ += __shfl_xor(p1_, o_);           \
        }                                                                     \
        if (valid) {                                                          \
            float mu_   = a_ * (1.f / 128.f);                                 \
            float var_  = q_ * (1.f / 128.f) - mu_ * mu_;                     \
            float rstd_ = rsqrtf(var_ + EPSLN);                               \
            float sc0_  = fmaf(rstd_, p0_ - mu_ * sgu0, d0);                  \
            float sc1_  = fmaf(rstd_, p1_ - mu_ * sgu1, d1);                  \
            float kv0_  = fmaf((xx.x - mu_) * rstd_, g0, hb0);                \
            float kv1_  = fmaf((xx.y - mu_) * rstd_, g1, hb1);                \
            float mn0_  = fmaxf(m0, sc0_);                                    \
            float cr0_  = exp2f(m0 - mn0_);                                   \
            float pp0_  = exp2f(sc0_ - mn0_);                                 \
            m0 = mn0_; l0 = fmaf(l0, cr0_, pp0_);                             \
            w00 = fmaf(w00, cr0_, pp0_ * kv0_);                               \
            w01 = fmaf(w01, cr0_, pp0_ * kv1_);                               \
            float mn1_  = fmaxf(m1, sc1_);                                    \
            float cr1_  = exp2f(m1 - mn1_);                                   \
            float pp1_  = exp2f(sc1_ - mn1_);                                 \
            m1 = mn1_; l1 = fmaf(l1, cr1_, pp1_);                             \
            w10 = fmaf(w10, cr1_, pp1_ * kv0_);                               \
            w11 = fmaf(w11, cr1_, pp1_ * kv1_);                               \
        }                                                                     \
    }

    float2 xr0 = make_float2(0.f, 0.f), xr1 = xr0, xr2 = xr0, xr3 = xr0;
    if (0 < cnt) xr0 = kf2[s_idx[wave][0] * 64 + lane];
    if (1 < cnt) xr1 = kf2[s_idx[wave][1] * 64 + lane];
    if (2 < cnt) xr2 = kf2[s_idx[wave][2] * 64 + lane];
    if (3 < cnt) xr3 = kf2[s_idx[wave][3] * 64 + lane];

    for (int t = 0; t < cnt; t += 4) {
        float2 xn0 = make_float2(0.f, 0.f), xn1 = xn0, xn2 = xn0, xn3 = xn0;
        if (t + 4 < cnt) xn0 = kf2[s_idx[wave][t + 4] * 64 + lane];
        if (t + 5 < cnt) xn1 = kf2[s_idx[wave][t + 5] * 64 + lane];
        if (t + 6 < cnt) xn2 = kf2[s_idx[wave][t + 6] * 64 + lane];
        if (t + 7 < cnt) xn3 = kf2[s_idx[wave][t + 7] * 64 + lane];

        ROW_STEP(xr0, true);
        ROW_STEP(xr1, (t + 1) < cnt);
        ROW_STEP(xr2, (t + 2) < cnt);
        ROW_STEP(xr3, (t + 3) < cnt);

        xr0 = xn0; xr1 = xn1; xr2 = xn2; xr3 = xn3;
    }
    #undef ROW_STEP

    // ---------- merge 4 waves' online-softmax partials ----------
    s_w[wave][0][c0i] = w00; s_w[wave][0][c1i] = w01;
    s_w[wave][1][c0i] = w10; s_w[wave][1][c1i] = w11;
    if (lane == 0) {
        s_ml[wave][0][0] = m0; s_ml[wave][0][1] = l0;
        s_ml[wave][1][0] = m1; s_ml[wave][1][1] = l1;
    }
    __syncthreads();

    if (tid < 128) {
        #pragma unroll
        for (int h = 0; h < 2; ++h) {
            float mg = fmaxf(fmaxf(s_ml[0][h][0], s_ml[1][h][0]),
                             fmaxf(s_ml[2][h][0], s_ml[3][h][0]));
            float lt = 0.f, wt = 0.f;
            #pragma unroll
            for (int wv = 0; wv < 4; ++wv) {
                float e = exp2f(s_ml[wv][h][0] - mg);
                lt += s_ml[wv][h][1] * e;
                wt += s_w[wv][h][tid] * e;
            }
            s_wn[h][tid] = wt / lt;
        }
    }
    __syncthreads();

    // ctx = (w/l) @ Wv + bv
    if (tid < 128) {
        int h = tid >> 6;
        float acc = bv[tid];
        #pragma unroll 4
        for (int c = 0; c < 128; ++c) acc = fmaf(s_wn[h][c], Wv[c * 128 + tid], acc);
        s_ctx[tid] = acc;
    }
    __syncthreads();

    // attn_out = gelu(ctx @ Wo + bo); q_atten_final = q1 + attn_out
    if (tid < 128) {
        float acc = bo[tid];
        #pragma unroll 4
        for (int c = 0; c < 128; ++c) acc = fmaf(s_ctx[c], Wo[c * 128 + tid], acc);
        float qa = s_q1[tid] + gelu_exact(acc);
        s_qa[tid] = qa;
        s_sc[tid] = qa * scale_w[tid];
    }
    __syncthreads();

    // LN2(q_atten_final) over 128
    float v2 = (tid < 128) ? s_qa[tid] : 0.0f;
    rs = v2; rss = v2 * v2;
    #pragma unroll
    for (int o = 32; o >= 1; o >>= 1) { rs += __shfl_xor(rs, o); rss += __shfl_xor(rss, o); }
    __syncthreads();                      // protect s_red reuse
    if (lane == 0) { s_red[wave * 2] = rs; s_red[wave * 2 + 1] = rss; }
    __syncthreads();
    {
        float sum  = s_red[0] + s_red[2] + s_red[4] + s_red[6];
        float ssum = s_red[1] + s_red[3] + s_red[5] + s_red[7];
        float mu   = sum * (1.0f / 128.0f);
        float var  = ssum * (1.0f / 128.0f) - mu * mu;
        float rstd = rsqrtf(var + EPSLN);
        if (tid < 128) s_qn2[tid] = (v2 - mu) * rstd * ln2_g[tid] + ln2_b[tid];
    }
    __syncthreads();

    // q_out = q_feats + gelu(qn2 @ W2 + b2)   (256 outputs, one per thread)
    {
        float acc = b2[tid];
        #pragma unroll 4
        for (int c = 0; c < 128; ++c) acc = fmaf(s_qn2[c], W2[c * 256 + tid], acc);
        q_out[b * LQD_ + tid] = q_feats[b * LQD_ + tid] + gelu_exact(acc);
    }

    // ---------- phase 2: stream column b of k_out ----------
    // k_out[b2, b, :] = k_feats[b2, b, :] + sc[b, :]   for b2 = 0..1023
    // thread layout: c4 = tid&31 (float4 within the 128-f32 row), r = tid>>5
    {
        const int c4 = tid & 31;
        const int r0 = tid >> 5;
        const float4 sv = ((const float4*)s_sc)[c4];
        const size_t colbase = (size_t)b * 32 + c4;
        const float4* __restrict__ kin4  = (const float4*)k_feats;
        float4*       __restrict__ kout4 = (float4*)k_out;
        #pragma unroll 4
        for (int b2 = r0; b2 < B_; b2 += 8) {
            size_t o = (size_t)b2 * (LK_ * 32) + colbase;
            float4 kx = kin4[o];
            float4 ov = make_float4(kx.x + sv.x, kx.y + sv.y, kx.z + sv.z, kx.w + sv.w);
            kout4[o] = ov;
        }
    }
}

extern "C" void kernel_launch(void* const* d_in, const int* in_sizes, int n_in,
                              void* d_out, int out_size, void* d_ws, size_t ws_size,
                              hipStream_t stream)
{
    (void)in_sizes; (void)n_in; (void)out_size; (void)d_ws; (void)ws_size;
    const float* q_feats = (const float*)d_in[0];
    const float* k_feats = (const float*)d_in[1];
    const int*   msk     = (const int*)d_in[2];
    const float* ln1_g   = (const float*)d_in[3];
    const float* ln1_b   = (const float*)d_in[4];
    const float* W1      = (const float*)d_in[5];
    const float* b1      = (const float*)d_in[6];
    const float* lnq_g   = (const float*)d_in[7];
    const float* lnq_b   = (const float*)d_in[8];
    const float* lnk_g   = (const float*)d_in[9];
    const float* lnk_b   = (const float*)d_in[10];
    const float* Wq      = (const float*)d_in[11];
    const float* bq      = (const float*)d_in[12];
    const float* Wk      = (const float*)d_in[13];
    const float* bk      = (const float*)d_in[14];
    const float* Wv      = (const float*)d_in[15];
    const float* bv      = (const float*)d_in[16];
    const float* Wo      = (const float*)d_in[17];
    const float* bo      = (const float*)d_in[18];
    const float* scale_w = (const float*)d_in[19];
    const float* ln2_g   = (const float*)d_in[20];
    const float* ln2_b   = (const float*)d_in[21];
    const float* W2      = (const float*)d_in[22];
    const float* b2      = (const float*)d_in[23];

    float* q_out = (float*)d_out;                           // 1024*256
    float* k_out = (float*)d_out + (size_t)B_ * LQD_;       // 1024*1024*128

    fused_joint_kernel<<<B_, 256, 0, stream>>>(
        q_feats, k_feats, msk, ln1_g, ln1_b, W1, b1, lnq_g, lnq_b,
        lnk_g, lnk_b, Wq, bq, Wk, bk, Wv, bv, Wo, bo, scale_w,
        ln2_g, ln2_b, W2, b2, q_out, k_out);
}